// Round 5
// baseline (204.311 us; speedup 1.0000x reference)
//
#include <hip/hip_runtime.h>
#include <math.h>

// smooth_step constants: LOW = pi/2 - pi/8, ramp width TW = pi/4
#define LOW_F   1.1780972450961724f
#define INV_TW  1.2732395447351628f   // 4/pi
#define WP_K    7.639437268410977f    // 6 * INV_TW  (dw/dtheta = 6 t (1-t) / TW)

typedef float floatx4 __attribute__((ext_vector_type(4)));  // builtin-compatible vec4

// Branchless acos, Cephes single-precision asin core (~1-2 ulp).
__device__ __forceinline__ float fast_acos(float x) {
    float s = __builtin_fabsf(x);
    bool big = s > 0.5f;
    float z = big ? fmaf(-0.5f, s, 0.5f) : x * x;
    float r = big ? __builtin_amdgcn_sqrtf(z) : s;
    float p = fmaf(z, 4.2163199048e-2f, 2.4181311049e-2f);
    p = fmaf(z, p, 4.5470025998e-2f);
    p = fmaf(z, p, 7.4953002686e-2f);
    p = fmaf(z, p, 1.6666752422e-1f);
    float asn = fmaf(r * z, p, r);
    float t2 = 2.0f * asn;
    float rb = (x >= 0.0f) ? t2 : (3.14159274f - t2);
    float rs = (x >= 0.0f) ? (1.57079637f - asn) : (1.57079637f + asn);
    return big ? rb : rs;
}

// Analytic velocity = -grad U  (calibrated R3: absmax 0.50 vs threshold 2.04)
__device__ __forceinline__ void point_velocity(float x, float y, float z,
                                               float a, float b,
                                               float dx, float dy, float dz,
                                               float& vx, float& vy, float& vz) {
    float r2 = x * x + y * y + z * z;
    float r = __builtin_amdgcn_sqrtf(r2);
    float invr = __builtin_amdgcn_rcpf(r);
    float dot = (x * dx + y * dy + z * dz) * invr;
    dot = fminf(fmaxf(dot, -1.0f), 1.0f);
    float theta = fast_acos(dot);

    float t = (theta - LOW_F) * INV_TW;
    t = fminf(fmaxf(t, 0.0f), 1.0f);
    float w = t * t * (3.0f - 2.0f * t);
    float one_m_w = 1.0f - w;
    float wp = WP_K * t * (1.0f - t);              // dw/dtheta (0 outside ramp)

    float th2 = theta * theta;
    float k1 = fmaf(b * th2, one_m_w, a);          // a + b th^2 (1-w)

    float sin2 = fmaf(-dot, dot, 1.0f);            // 1 - dot^2
    float sinth = __builtin_amdgcn_sqrtf(fmaxf(sin2, 0.0f));
    float rcpsin = __builtin_amdgcn_rcpf(fmaxf(sinth, 1e-30f));
    float num = fmaf(2.0f * theta, one_m_w, -th2 * wp);  // 2 th (1-w) - th^2 w' ; ==0 at dot=+-1
    float k2 = (r * 0.5f * b) * num * rcpsin;

    float m = dot * invr;                          // dot / r
    float gx = fmaf(-m, x, dx);                    // d - dot * p_hat
    float gy = fmaf(-m, y, dy);
    float gz = fmaf(-m, z, dz);

    float ovx = fmaf(-k1, x, k2 * gx);
    float ovy = fmaf(-k1, y, k2 * gy);
    float ovz = fmaf(-k1, z, k2 * gz);

    bool origin = (r2 == 0.0f);
    vx = origin ? 0.0f : ovx;
    vy = origin ? 0.0f : ovy;
    vz = origin ? 0.0f : ovz;
}

// Persistent-grid pipelined kernel: 2048 blocks x 256 thr = 32 waves/CU resident.
// Each thread grid-strides over quads (4 points = 3 float4). Next iteration's
// loads are issued before computing the current one (regs double-buffered).
extern "C" __global__ void __launch_bounds__(256)
canyon3d_grad_kernel(const float* __restrict__ xyz,
                     const float* __restrict__ a_param,
                     const float* __restrict__ b_param,
                     const float* __restrict__ dir,
                     float* __restrict__ out,
                     int B) {
    int nquad = B >> 2;
    int tid = blockIdx.x * blockDim.x + threadIdx.x;
    int stride = gridDim.x * blockDim.x;

    float a = fminf(fmaxf(a_param[0], 0.0f), 20.0f);
    float b = fminf(fmaxf(b_param[0], 0.0f), 20.0f);
    float dx = dir[0], dy = dir[1], dz = dir[2];

    const floatx4* in4 = (const floatx4*)xyz;
    floatx4* out4 = (floatx4*)out;

    int q = tid;
    if (q < nquad) {
        floatx4 A  = in4[3 * q + 0];
        floatx4 Bv = in4[3 * q + 1];
        floatx4 C  = in4[3 * q + 2];
        for (;;) {
            int qn = q + stride;
            bool more = qn < nquad;
            floatx4 An, Bn, Cn;
            if (more) {                      // prefetch next iteration
                An = in4[3 * qn + 0];
                Bn = in4[3 * qn + 1];
                Cn = in4[3 * qn + 2];
            }

            float o0, o1, o2, o3, o4, o5, o6, o7, o8, o9, o10, o11;
            point_velocity(A.x, A.y, A.z,   a, b, dx, dy, dz, o0, o1, o2);
            point_velocity(A.w, Bv.x, Bv.y, a, b, dx, dy, dz, o3, o4, o5);
            point_velocity(Bv.z, Bv.w, C.x, a, b, dx, dy, dz, o6, o7, o8);
            point_velocity(C.y, C.z, C.w,   a, b, dx, dy, dz, o9, o10, o11);

            floatx4 O0 = {o0, o1, o2, o3};
            floatx4 O1 = {o4, o5, o6, o7};
            floatx4 O2 = {o8, o9, o10, o11};
            __builtin_nontemporal_store(O0, &out4[3 * q + 0]);
            __builtin_nontemporal_store(O1, &out4[3 * q + 1]);
            __builtin_nontemporal_store(O2, &out4[3 * q + 2]);

            if (!more) break;
            q = qn; A = An; Bv = Bn; C = Cn;
        }
    }

    // tail points (B % 4)
    int done = nquad << 2;
    int rem = B - done;
    if (tid < rem) {
        int i = done + tid;
        float x = xyz[3 * i], y = xyz[3 * i + 1], z = xyz[3 * i + 2];
        float vx, vy, vz;
        point_velocity(x, y, z, a, b, dx, dy, dz, vx, vy, vz);
        out[3 * i] = vx; out[3 * i + 1] = vy; out[3 * i + 2] = vz;
    }
}

extern "C" void kernel_launch(void* const* d_in, const int* in_sizes, int n_in,
                              void* d_out, int out_size, void* d_ws, size_t ws_size,
                              hipStream_t stream) {
    const float* xyz = (const float*)d_in[0];
    const float* a_param = (const float*)d_in[1];
    const float* b_param = (const float*)d_in[2];
    const float* dir = (const float*)d_in[3];
    float* out = (float*)d_out;

    int B = in_sizes[0] / 3;
    // Persistent grid: 8 blocks/CU x 256 CUs = 2048 blocks (full residency, one round)
    int nquad = B / 4;
    int blocks = 2048;
    int maxBlocks = (nquad + 255) / 256;
    if (blocks > maxBlocks) blocks = maxBlocks > 0 ? maxBlocks : 1;
    canyon3d_grad_kernel<<<dim3(blocks), dim3(256), 0, stream>>>(xyz, a_param, b_param, dir, out, B);
}

// Round 7
// 180.859 us; speedup vs baseline: 1.1297x; 1.1297x over previous
//
#include <hip/hip_runtime.h>
#include <math.h>

// smooth_step constants: LOW = pi/2 - pi/8, ramp width TW = pi/4
#define LOW_F   1.1780972450961724f
#define INV_TW  1.2732395447351628f   // 4/pi
#define WP_K    7.639437268410977f    // 6 * INV_TW  (dw/dtheta = 6 t (1-t) / TW)

typedef float floatx4 __attribute__((ext_vector_type(4)));

// Branchless acos, Cephes single-precision asin core (~1-2 ulp).
__device__ __forceinline__ float fast_acos(float x) {
    float s = __builtin_fabsf(x);
    bool big = s > 0.5f;
    float z = big ? fmaf(-0.5f, s, 0.5f) : x * x;
    float r = big ? __builtin_amdgcn_sqrtf(z) : s;
    float p = fmaf(z, 4.2163199048e-2f, 2.4181311049e-2f);
    p = fmaf(z, p, 4.5470025998e-2f);
    p = fmaf(z, p, 7.4953002686e-2f);
    p = fmaf(z, p, 1.6666752422e-1f);
    float asn = fmaf(r * z, p, r);
    float t2 = 2.0f * asn;
    float rb = (x >= 0.0f) ? t2 : (3.14159274f - t2);
    float rs = (x >= 0.0f) ? (1.57079637f - asn) : (1.57079637f + asn);
    return big ? rb : rs;
}

// Analytic velocity = -grad U  (calibrated R3: absmax 0.50 vs threshold 2.04)
__device__ __forceinline__ void point_velocity(float x, float y, float z,
                                               float a, float b,
                                               float dx, float dy, float dz,
                                               float& vx, float& vy, float& vz) {
    float r2 = x * x + y * y + z * z;
    float r = __builtin_amdgcn_sqrtf(r2);
    float invr = __builtin_amdgcn_rcpf(r);
    float dot = (x * dx + y * dy + z * dz) * invr;
    dot = fminf(fmaxf(dot, -1.0f), 1.0f);
    float theta = fast_acos(dot);

    float t = (theta - LOW_F) * INV_TW;
    t = fminf(fmaxf(t, 0.0f), 1.0f);
    float w = t * t * (3.0f - 2.0f * t);
    float one_m_w = 1.0f - w;
    float wp = WP_K * t * (1.0f - t);              // dw/dtheta (0 outside ramp)

    float th2 = theta * theta;
    float k1 = fmaf(b * th2, one_m_w, a);          // a + b th^2 (1-w)

    float sin2 = fmaf(-dot, dot, 1.0f);            // 1 - dot^2
    float sinth = __builtin_amdgcn_sqrtf(fmaxf(sin2, 0.0f));
    float rcpsin = __builtin_amdgcn_rcpf(fmaxf(sinth, 1e-30f));
    float num = fmaf(2.0f * theta, one_m_w, -th2 * wp);  // 2 th (1-w) - th^2 w' ; ==0 at dot=+-1
    float k2 = (r * 0.5f * b) * num * rcpsin;

    float m = dot * invr;                          // dot / r
    float gx = fmaf(-m, x, dx);                    // d - dot * p_hat
    float gy = fmaf(-m, y, dy);
    float gz = fmaf(-m, z, dz);

    float ovx = fmaf(-k1, x, k2 * gx);
    float ovy = fmaf(-k1, y, k2 * gy);
    float ovz = fmaf(-k1, z, k2 * gz);

    bool origin = (r2 == 0.0f);
    vx = origin ? 0.0f : ovx;
    vy = origin ? 0.0f : ovy;
    vz = origin ? 0.0f : ovz;
}

// LDS-staged layout transform: every global VMEM instruction is lane-contiguous
// (16B/lane, 1KB/wave-instr). Per-thread AoS access happens in LDS instead
// (48B/thread reads = 2-way bank aliasing = free). 12 KB LDS/block, 8 blk/CU.
extern "C" __global__ void __launch_bounds__(256)
canyon3d_lds_kernel(const float* __restrict__ xyz,
                    const float* __restrict__ a_param,
                    const float* __restrict__ b_param,
                    const float* __restrict__ dir,
                    float* __restrict__ out,
                    int B) {
    __shared__ floatx4 lds4[768];                  // 256 quads * 3 float4 = 12 KB
    int nquad = B >> 2;
    int t = threadIdx.x;
    int qbase = blockIdx.x << 8;                   // 256 quads per block

    float a = fminf(fmaxf(a_param[0], 0.0f), 20.0f);
    float b = fminf(fmaxf(b_param[0], 0.0f), 20.0f);
    float dx = dir[0], dy = dir[1], dz = dir[2];

    const floatx4* in4 = (const floatx4*)xyz;
    floatx4* out4 = (floatx4*)out;

    if (qbase + 256 <= nquad) {
        int fbase = 3 * qbase;                     // float4 index of block tile
        // stage in: 3 fully-coalesced float4 loads
        lds4[t]       = in4[fbase + t];
        lds4[t + 256] = in4[fbase + 256 + t];
        lds4[t + 512] = in4[fbase + 512 + t];
        __syncthreads();

        float* lf = (float*)lds4;
        floatx4 P0 = *(const floatx4*)(lf + 12 * t);      // own 4 points (48B)
        floatx4 P1 = *(const floatx4*)(lf + 12 * t + 4);
        floatx4 P2 = *(const floatx4*)(lf + 12 * t + 8);

        float o0, o1, o2, o3, o4, o5, o6, o7, o8, o9, o10, o11;
        point_velocity(P0.x, P0.y, P0.z, a, b, dx, dy, dz, o0, o1, o2);
        point_velocity(P0.w, P1.x, P1.y, a, b, dx, dy, dz, o3, o4, o5);
        point_velocity(P1.z, P1.w, P2.x, a, b, dx, dy, dz, o6, o7, o8);
        point_velocity(P2.y, P2.z, P2.w, a, b, dx, dy, dz, o9, o10, o11);

        // write results back to own LDS slots (same addresses this thread read)
        floatx4 O0 = {o0, o1, o2, o3};
        floatx4 O1 = {o4, o5, o6, o7};
        floatx4 O2 = {o8, o9, o10, o11};
        *(floatx4*)(lf + 12 * t)     = O0;
        *(floatx4*)(lf + 12 * t + 4) = O1;
        *(floatx4*)(lf + 12 * t + 8) = O2;
        __syncthreads();

        // stage out: 3 fully-coalesced float4 stores
        out4[fbase + t]       = lds4[t];
        out4[fbase + 256 + t] = lds4[t + 256];
        out4[fbase + 512 + t] = lds4[t + 512];
    } else {
        // partial last block: scalar per-point
        for (int i = (qbase << 2) + t; i < B; i += 256) {
            float x = xyz[3 * i], y = xyz[3 * i + 1], z = xyz[3 * i + 2];
            float vx, vy, vz;
            point_velocity(x, y, z, a, b, dx, dy, dz, vx, vy, vz);
            out[3 * i] = vx; out[3 * i + 1] = vy; out[3 * i + 2] = vz;
        }
    }
}

extern "C" void kernel_launch(void* const* d_in, const int* in_sizes, int n_in,
                              void* d_out, int out_size, void* d_ws, size_t ws_size,
                              hipStream_t stream) {
    const float* xyz = (const float*)d_in[0];
    const float* a_param = (const float*)d_in[1];
    const float* b_param = (const float*)d_in[2];
    const float* dir = (const float*)d_in[3];
    float* out = (float*)d_out;

    int B = in_sizes[0] / 3;
    int nquad = (B + 3) / 4;
    int blocks = (nquad + 255) / 256;
    canyon3d_lds_kernel<<<dim3(blocks), dim3(256), 0, stream>>>(xyz, a_param, b_param, dir, out, B);
}